// Round 2
// baseline (201.814 us; speedup 1.0000x reference)
//
#include <hip/hip_runtime.h>

#define B_ 16
#define N_ 4096
#define F_ 8
#define H_ 64
#define C_ 256
#define FH 512      // F_*H_
#define CAP 256     // max nodes per segment (binomial mean 16, sd 4; 256 unreachable)

// ---------------------------------------------------------------------------
// One block of 256 threads (4 waves) per (b, c). Grid = B_*C_ = 4096,
// ~6 blocks/CU resident (launch_bounds 256,6) -> 2.7x oversubscription for
// segment-size load balancing (unchanged from R1).
//
// R2 change: row-per-32-lane-group, 4 rows per wave ISSUED TOGETHER.
//  * R1 ran 2 sequential pair-iterations per wave; each was a serial chain
//    load(4KB)->vmcnt(0)->dot->6x shfl (~240cy)->exp->FMA, so loads were in
//    flight only ~half the wave's lifetime -> ~3.2 TB/s (50% of achievable).
//  * Now: lane pos=l&31 covers row elements 4*pos+128k (k=0..3); the W quad
//    is identical for all k ((4*pos+128k)%64 == 4*pos%64). Each 32-lane
//    group owns one row; x2 unroll -> 4 rows (8 KB) per wave per iteration,
//    all 8 wave-loads issued before any use. Typical m=16 -> ONE iteration.
//  * Lane-reduce: 5 shfl_xor steps (16..1) reduce both groups' rows in the
//    same instructions; one exp per 2 rows. Cross-group: shfl_xor(.,32).
//  * Partial-iteration clamp slots get guarded loads (skip ~9% waste BW).
//
// Phase 3: wave partials (4 float4/lane over 32 lanes) + esum -> LDS
// [wave][k][pos] (lane-consecutive, conflict-free); 128 threads combine,
// normalize by 1/esum, store (out float4 idx == t, coalesced).
//
// x read exactly once; no workspace; one dispatch.
// ---------------------------------------------------------------------------
__device__ __forceinline__ float dot4(const float4 a, const float4 w) {
    return (a.x * w.x + a.y * w.y) + (a.z * w.z + a.w * w.w);
}

__global__ __launch_bounds__(256, 6) void fused_pool_kernel(
    const float* __restrict__ x, const float* __restrict__ W,
    const float* __restrict__ bias, const int* __restrict__ seg,
    float* __restrict__ out)
{
    int c    = blockIdx.x & (C_ - 1);
    int b    = blockIdx.x >> 8;       // batch 0..15
    int t    = threadIdx.x;           // 0..255
    int wave = t >> 6;                // 0..3
    int lane = t & 63;
    int grp  = lane >> 5;             // 0..1 (32-lane row group)
    int pos  = lane & 31;

    __shared__ int    list[CAP];
    __shared__ int    cnt;
    __shared__ float4 acc_sh[4][4][32];   // [wave][k][pos] - lane-consecutive
    __shared__ float  es_sh[4];

    if (t == 0) cnt = 0;
    __syncthreads();

    // ---- Phase 1: membership scan (16 KB seg, L2-resident broadcast) ----
    const int4* seg4 = (const int4*)seg;
#pragma unroll
    for (int k = 0; k < N_ / (256 * 4); k++) {
        int i4 = t + k * 256;
        int4 s4 = seg4[i4];
        int n0 = i4 * 4;
        if (s4.x == c) { int p = atomicAdd(&cnt, 1); if (p < CAP) list[p] = n0; }
        if (s4.y == c) { int p = atomicAdd(&cnt, 1); if (p < CAP) list[p] = n0 + 1; }
        if (s4.z == c) { int p = atomicAdd(&cnt, 1); if (p < CAP) list[p] = n0 + 2; }
        if (s4.w == c) { int p = atomicAdd(&cnt, 1); if (p < CAP) list[p] = n0 + 3; }
    }
    __syncthreads();
    int m = cnt;
    if (m > CAP) m = CAP;

    // ---- Phase 2: 4 rows per wave-iteration, one row per 32-lane group ----
    float4 w4 = *(const float4*)(W + ((4 * pos) & (H_ - 1)));
    float  bb = bias[0];
    const float4* x4 = (const float4*)x;
    size_t batch_base = (size_t)b * (N_ * (FH / 4));

    float4 acc0 = {0,0,0,0}, acc1 = {0,0,0,0}, acc2 = {0,0,0,0}, acc3 = {0,0,0,0};
    float  esum = 0.0f;

    for (int base = wave * 4; base < m; base += 16) {
        int r0 = base + grp;          // rows base, base+1
        int r1 = base + 2 + grp;      // rows base+2, base+3
        int a0 = (r0 < m), a1 = (r1 < m);
        int cr0 = a0 ? r0 : (m - 1);
        int cr1 = a1 ? r1 : (m - 1);
        const float4* p0 = x4 + (batch_base + ((size_t)list[cr0] << 7) + pos);
        const float4* p1 = x4 + (batch_base + ((size_t)list[cr1] << 7) + pos);

        float4 v00, v01, v02, v03, v10, v11, v12, v13;
        if (a0) { v00 = p0[0]; v01 = p0[32]; v02 = p0[64]; v03 = p0[96]; }
        else    { v00 = v01 = v02 = v03 = make_float4(0.f, 0.f, 0.f, 0.f); }
        if (a1) { v10 = p1[0]; v11 = p1[32]; v12 = p1[64]; v13 = p1[96]; }
        else    { v10 = v11 = v12 = v13 = make_float4(0.f, 0.f, 0.f, 0.f); }

        float d0 = (dot4(v00, w4) + dot4(v01, w4)) + (dot4(v02, w4) + dot4(v03, w4));
        float d1 = (dot4(v10, w4) + dot4(v11, w4)) + (dot4(v12, w4) + dot4(v13, w4));
#pragma unroll
        for (int off = 16; off > 0; off >>= 1) {
            d0 += __shfl_xor(d0, off);
            d1 += __shfl_xor(d1, off);
        }
        float e0 = a0 ? __expf(d0 * (1.0f / F_) + bb) : 0.0f;
        float e1 = a1 ? __expf(d1 * (1.0f / F_) + bb) : 0.0f;
        esum += e0 + e1;
        acc0.x += e0 * v00.x + e1 * v10.x; acc0.y += e0 * v00.y + e1 * v10.y;
        acc0.z += e0 * v00.z + e1 * v10.z; acc0.w += e0 * v00.w + e1 * v10.w;
        acc1.x += e0 * v01.x + e1 * v11.x; acc1.y += e0 * v01.y + e1 * v11.y;
        acc1.z += e0 * v01.z + e1 * v11.z; acc1.w += e0 * v01.w + e1 * v11.w;
        acc2.x += e0 * v02.x + e1 * v12.x; acc2.y += e0 * v02.y + e1 * v12.y;
        acc2.z += e0 * v02.z + e1 * v12.z; acc2.w += e0 * v02.w + e1 * v12.w;
        acc3.x += e0 * v03.x + e1 * v13.x; acc3.y += e0 * v03.y + e1 * v13.y;
        acc3.z += e0 * v03.z + e1 * v13.z; acc3.w += e0 * v03.w + e1 * v13.w;
    }

    // ---- cross-group combine: grp0 + grp1 via xor-32 shfl adds ----
    acc0.x += __shfl_xor(acc0.x, 32); acc0.y += __shfl_xor(acc0.y, 32);
    acc0.z += __shfl_xor(acc0.z, 32); acc0.w += __shfl_xor(acc0.w, 32);
    acc1.x += __shfl_xor(acc1.x, 32); acc1.y += __shfl_xor(acc1.y, 32);
    acc1.z += __shfl_xor(acc1.z, 32); acc1.w += __shfl_xor(acc1.w, 32);
    acc2.x += __shfl_xor(acc2.x, 32); acc2.y += __shfl_xor(acc2.y, 32);
    acc2.z += __shfl_xor(acc2.z, 32); acc2.w += __shfl_xor(acc2.w, 32);
    acc3.x += __shfl_xor(acc3.x, 32); acc3.y += __shfl_xor(acc3.y, 32);
    acc3.z += __shfl_xor(acc3.z, 32); acc3.w += __shfl_xor(acc3.w, 32);
    esum  += __shfl_xor(esum, 32);

    if (lane < 32) {
        acc_sh[wave][0][pos] = acc0;
        acc_sh[wave][1][pos] = acc1;
        acc_sh[wave][2][pos] = acc2;
        acc_sh[wave][3][pos] = acc3;
        if (lane == 0) es_sh[wave] = esum;
    }
    __syncthreads();

    // ---- Phase 3: cross-wave combine, normalize, store ----
    if (t < 128) {
        int kk = t >> 5, pp = t & 31;     // out float4 idx = pp + 32*kk == t
        float es  = es_sh[0] + es_sh[1] + es_sh[2] + es_sh[3];
        float inv = (m > 0) ? 1.0f / es : 0.0f;   // empty segment -> zeros
        float4 s0 = acc_sh[0][kk][pp];
        float4 s1 = acc_sh[1][kk][pp];
        float4 s2 = acc_sh[2][kk][pp];
        float4 s3 = acc_sh[3][kk][pp];
        float4 r;
        r.x = (s0.x + s1.x + s2.x + s3.x) * inv;
        r.y = (s0.y + s1.y + s2.y + s3.y) * inv;
        r.z = (s0.z + s1.z + s2.z + s3.z) * inv;
        r.w = (s0.w + s1.w + s2.w + s3.w) * inv;
        size_t ob = ((size_t)(b * C_ + c)) * (FH / 4);
        ((float4*)out)[ob + t] = r;
    }
}

// ---------------------------------------------------------------------------
extern "C" void kernel_launch(void* const* d_in, const int* in_sizes, int n_in,
                              void* d_out, int out_size, void* d_ws, size_t ws_size,
                              hipStream_t stream)
{
    const float* x    = (const float*)d_in[0];
    const float* W    = (const float*)d_in[1];
    const float* bias = (const float*)d_in[2];
    const int*   seg  = (const int*)d_in[3];
    float* out = (float*)d_out;

    fused_pool_kernel<<<B_ * C_, 256, 0, stream>>>(x, W, bias, seg, out);
}